// Round 1
// baseline (59.209 us; speedup 1.0000x reference)
//
#include <hip/hip_runtime.h>

// Depthwise cross-correlation, B*C = 32768 independent planes:
//   x[32][32] (*) k[8][8] -> out[25][25]
// softmax(weight) sums to exactly 1.0 -> output == correlation; weight unused.

#define NPLANES (128 * 256)
#define BPB 10          // planes per block
#define PS  1100        // LDS plane stride in dwords: 1024 (x) + 64 (k) + 12 pad; 1100%32=12 de-aliases planes
#define OH 25
#define OW 25

__global__ __launch_bounds__(256, 3)
void dwxcorr_kernel(const float* __restrict__ x,
                    const float* __restrict__ k,
                    float* __restrict__ out) {
    __shared__ float lds[BPB * PS];   // 44000 B -> 3 blocks/CU
    const int tid = threadIdx.x;
    const int plane0 = blockIdx.x * BPB;

    // ---- Stage x: BPB*1024 floats = 2560 float4, coalesced ----
#pragma unroll
    for (int it = 0; it < BPB; ++it) {
        const int idx = tid + it * 256;      // float4 index within block
        const int pb  = idx >> 8;            // 256 float4 per plane
        const int o4  = idx & 255;
        if (plane0 + pb < NPLANES) {
            const float4 v =
                reinterpret_cast<const float4*>(x)[(size_t)(plane0 + pb) * 256 + o4];
            float* dst = &lds[pb * PS + o4 * 4];
            dst[0] = v.x; dst[1] = v.y; dst[2] = v.z; dst[3] = v.w;
        }
    }
    // ---- Stage k: BPB*64 floats = 160 float4 ----
    if (tid < BPB * 16) {
        const int pb = tid >> 4;
        const int o4 = tid & 15;
        if (plane0 + pb < NPLANES) {
            const float4 v =
                reinterpret_cast<const float4*>(k)[(size_t)(plane0 + pb) * 16 + o4];
            float* dst = &lds[pb * PS + 1024 + o4 * 4];
            dst[0] = v.x; dst[1] = v.y; dst[2] = v.z; dst[3] = v.w;
        }
    }
    __syncthreads();

    // ---- Compute: thread = one output column (25 outputs) ----
    const int pb = tid / OW;     // 0..10
    const int ox = tid % OW;
    if (pb >= BPB) return;                       // tid 250..255 idle
    const int plane = plane0 + pb;
    if (plane >= NPLANES) return;                // tail block guard

    const float* __restrict__ xp = &lds[pb * PS];
    const float* __restrict__ kp = &lds[pb * PS + 1024];

    // Kernel -> registers (broadcast reads, reused 25x8x8 times)
    float kk[64];
#pragma unroll
    for (int i = 0; i < 64; ++i) kk[i] = kp[i];

    float acc[OH];
#pragma unroll
    for (int i = 0; i < OH; ++i) acc[i] = 0.f;

    // Each x row read once per thread; contributes to up to 8 output rows.
#pragma unroll
    for (int ar = 0; ar < 32; ++ar) {
        float xr[8];
        const float* row = &xp[ar * 32 + ox];
#pragma unroll
        for (int j = 0; j < 8; ++j) xr[j] = row[j];
#pragma unroll
        for (int ky = 0; ky < 8; ++ky) {
            const int oy = ar - ky;              // compile-time with full unroll
            if (oy >= 0 && oy < OH) {
#pragma unroll
                for (int kx = 0; kx < 8; ++kx)
                    acc[oy] = fmaf(xr[kx], kk[ky * 8 + kx], acc[oy]);
            }
        }
    }

    // Coalesced stores: lanes (consecutive ox) write consecutive addresses.
    float* op = out + (size_t)plane * (OH * OW);
#pragma unroll
    for (int oy = 0; oy < OH; ++oy)
        op[oy * OW + ox] = acc[oy];
}

extern "C" void kernel_launch(void* const* d_in, const int* in_sizes, int n_in,
                              void* d_out, int out_size, void* d_ws, size_t ws_size,
                              hipStream_t stream) {
    const float* x = (const float*)d_in[0];
    const float* k = (const float*)d_in[1];
    // d_in[2] (weight) unused: softmax weights sum to exactly 1.
    float* out = (float*)d_out;
    const int nblocks = (NPLANES + BPB - 1) / BPB;   // 3277
    dwxcorr_kernel<<<nblocks, 256, 0, stream>>>(x, k, out);
}